// Round 3
// baseline (1319.078 us; speedup 1.0000x reference)
//
#include <hip/hip_runtime.h>

// ---------------------------------------------------------------------------
// EnterpriseGNN: 3-layer GCN on MI355X.
//   out[i] = dinv[i]*(sum_{e:dst=i} w_e*dinv[src_e]*u[src_e]) + dinv[i]^2*u[i] + b
//   u = x@W, dinv = rsqrt(deg+1), deg = sum_{e:dst=i} w_e.
//
// R1: per-(edge,feature) global atomics -> 400 MB write-through, 332 us.
// R2: CSR build's random global atomics (hist 278 us, WRITE=200 MB) became
//     the bottleneck: random-line atomicAdd runs at ~23 G/s.
// R3: ZERO random global atomics. One-pass bucket sort by dst>>8 (391
//     buckets x 256 nodes): LDS block-histograms -> 2 small scans -> scatter
//     into disjoint per-(block,bucket) ranges with LDS cursors. One WG owns
//     one bucket: aggregates into a 256xF LDS tile (ds_add_f32), then ONE
//     coalesced global store. deg from records via LDS tile. dinv/bias/relu
//     fused in agg epilogue. No memsets.
// ---------------------------------------------------------------------------

#define G 256          // producer blocks for hist/scatter
#define BLK 256

// --- bucket build ----------------------------------------------------------

__global__ __launch_bounds__(256) void hist_kernel(
    const int* __restrict__ dst, int* __restrict__ blockHist, int E, int B) {
    __shared__ int hist[512];
    for (int i = threadIdx.x; i < B; i += 256) hist[i] = 0;
    __syncthreads();
    int per = (E + G - 1) / G;
    int e0 = blockIdx.x * per, e1 = min(e0 + per, E);
    for (int e = e0 + threadIdx.x; e < e1; e += 256)
        atomicAdd(&hist[((unsigned)dst[e]) >> 8], 1);
    __syncthreads();
    for (int i = threadIdx.x; i < B; i += 256)
        blockHist[i * G + blockIdx.x] = hist[i];
}

// exclusive scan over producers g for one bucket b; total -> bucketTotal[b]
__global__ __launch_bounds__(256) void scan_cols_kernel(
    int* __restrict__ blockHist, int* __restrict__ bucketTotal) {
    __shared__ int tmp[256];
    int b = blockIdx.x;
    int v = blockHist[b * G + threadIdx.x];
    tmp[threadIdx.x] = v;
    __syncthreads();
    for (int off = 1; off < 256; off <<= 1) {
        int t = (threadIdx.x >= off) ? tmp[threadIdx.x - off] : 0;
        __syncthreads();
        tmp[threadIdx.x] += t;
        __syncthreads();
    }
    blockHist[b * G + threadIdx.x] = tmp[threadIdx.x] - v;
    if (threadIdx.x == 255) bucketTotal[b] = tmp[255];
}

// exclusive scan of bucket totals (B <= 512), one block
__global__ void base_scan_kernel(const int* __restrict__ bucketTotal,
                                 int* __restrict__ bucketBase, int B, int E) {
    __shared__ int tmp[512];
    int v = (threadIdx.x < B) ? bucketTotal[threadIdx.x] : 0;
    tmp[threadIdx.x] = v;
    __syncthreads();
    for (int off = 1; off < 512; off <<= 1) {
        int t = (threadIdx.x >= off) ? tmp[threadIdx.x - off] : 0;
        __syncthreads();
        tmp[threadIdx.x] += t;
        __syncthreads();
    }
    if (threadIdx.x < B) bucketBase[threadIdx.x] = tmp[threadIdx.x] - v;
    if (threadIdx.x == 0) bucketBase[B] = E;
}

// rec.x = src | (dst&255)<<20 ; rec.y = bits(w). Disjoint cursor ranges per
// (block,bucket) -> no global atomics.
__global__ __launch_bounds__(256) void scatter_kernel(
    const int* __restrict__ src, const int* __restrict__ dst,
    const float* __restrict__ w, const int* __restrict__ blockHist,
    const int* __restrict__ bucketBase, uint2* __restrict__ recs,
    int E, int B) {
    __shared__ int cursor[512];
    for (int i = threadIdx.x; i < B; i += 256)
        cursor[i] = bucketBase[i] + blockHist[i * G + blockIdx.x];
    __syncthreads();
    int per = (E + G - 1) / G;
    int e0 = blockIdx.x * per, e1 = min(e0 + per, E);
    for (int e = e0 + threadIdx.x; e < e1; e += 256) {
        int d = dst[e];
        int b = ((unsigned)d) >> 8;
        int pos = atomicAdd(&cursor[b], 1);   // LDS atomic
        recs[pos] = make_uint2((unsigned)src[e] | ((unsigned)(d & 255) << 20),
                               __float_as_uint(w[e]));
    }
}

// deg per bucket via LDS tile -> dinv = rsqrt(deg+1)
__global__ __launch_bounds__(256) void degdinv_kernel(
    const int* __restrict__ bucketBase, const uint2* __restrict__ recs,
    float* __restrict__ dinv, int N) {
    __shared__ float deg[256];
    deg[threadIdx.x] = 0.f;
    __syncthreads();
    int b = blockIdx.x;
    int r0 = bucketBase[b], r1 = bucketBase[b + 1];
    for (int i = r0 + threadIdx.x; i < r1; i += 256) {
        uint2 rec = recs[i];
        atomicAdd(&deg[rec.x >> 20], __uint_as_float(rec.y));
    }
    __syncthreads();
    int n = b * 256 + threadIdx.x;
    if (n < N) dinv[n] = rsqrtf(deg[threadIdx.x] + 1.f);
}

// --- dense layers ----------------------------------------------------------

// u1 = x @ W1  (128 -> 32), unscaled
__global__ __launch_bounds__(256) void gemm1_kernel(
    const float* __restrict__ x, const float* __restrict__ W1,
    float* __restrict__ u1, int N) {
    __shared__ float sW[128 * 32];   // 16 KB
    __shared__ float sx[8][128];     // 4 KB
    for (int i = threadIdx.x; i < 128 * 32; i += BLK) sW[i] = W1[i];
    int node0 = blockIdx.x * 8;
    for (int i = threadIdx.x; i < 8 * 128; i += BLK) {
        int r = i >> 7, c = i & 127;
        int n = node0 + r;
        sx[r][c] = (n < N) ? x[(size_t)n * 128 + c] : 0.f;
    }
    __syncthreads();
    int local = threadIdx.x >> 5;
    int j = threadIdx.x & 31;
    int n = node0 + local;
    if (n < N) {
        float acc = 0.f;
#pragma unroll 16
        for (int k = 0; k < 128; k++) acc += sx[local][k] * sW[k * 32 + j];
        u1[(size_t)n * 32 + j] = acc;
    }
}

// u2 = h1 @ W2  (32 -> 16), unscaled
__global__ __launch_bounds__(256) void gemm2_kernel(
    const float* __restrict__ h1, const float* __restrict__ W2,
    float* __restrict__ u2, int N) {
    __shared__ float sW[32 * 16];
    __shared__ float sin_[16][32];
    for (int i = threadIdx.x; i < 32 * 16; i += BLK) sW[i] = W2[i];
    int node0 = blockIdx.x * 16;
    for (int i = threadIdx.x; i < 16 * 32; i += BLK) {
        int r = i >> 5, c = i & 31;
        int n = node0 + r;
        sin_[r][c] = (n < N) ? h1[(size_t)n * 32 + c] : 0.f;
    }
    __syncthreads();
    int local = threadIdx.x >> 4;
    int j = threadIdx.x & 15;
    int n = node0 + local;
    if (n < N) {
        float acc = 0.f;
#pragma unroll
        for (int k = 0; k < 32; k++) acc += sin_[local][k] * sW[k * 16 + j];
        u2[(size_t)n * 16 + j] = acc;
    }
}

// one WG per bucket: LDS-tile aggregation + fused self-loop/dinv/bias/relu
template <int F>
__global__ __launch_bounds__(256) void agg_kernel(
    const int* __restrict__ bucketBase, const uint2* __restrict__ recs,
    const float* __restrict__ u, const float* __restrict__ dinv,
    const float* __restrict__ bias, float* __restrict__ h, int N) {
    const int FS = F + 1;                    // LDS pad: conflict-free banks
    __shared__ float tile[256 * FS];
    for (int i = threadIdx.x; i < 256 * FS; i += 256) tile[i] = 0.f;
    __syncthreads();
    int b = blockIdx.x;
    int r0 = bucketBase[b], r1 = bucketBase[b + 1];
    const int EPB = 256 / F;                 // edges in flight per iteration
    int f = threadIdx.x & (F - 1);
    for (int i = r0 + (threadIdx.x / F); i < r1; i += EPB) {
        uint2 rec = recs[i];
        unsigned s  = rec.x & 0xFFFFFu;      // 20-bit src
        unsigned dl = rec.x >> 20;           // dst & 255
        float wdi = __uint_as_float(rec.y) * dinv[s];
        atomicAdd(&tile[dl * FS + f], wdi * u[(size_t)s * F + f]);  // ds_add
    }
    __syncthreads();
    int node0 = b * 256;
    for (int k = threadIdx.x; k < 256 * F; k += 256) {
        int loc = k / F, ff = k & (F - 1);
        int n = node0 + loc;
        if (n < N) {
            float di = dinv[n];
            float v = di * tile[loc * FS + ff] + di * di * u[(size_t)n * F + ff] + bias[ff];
            h[(size_t)n * F + ff] = fmaxf(v, 0.f);
        }
    }
}

// out = h2 @ Wout + bout   (16 -> 3)
__global__ __launch_bounds__(256) void final_kernel(
    const float* __restrict__ h2, const float* __restrict__ Wout,
    const float* __restrict__ bout, float* __restrict__ out, int N) {
    int n = blockIdx.x * blockDim.x + threadIdx.x;
    if (n >= N) return;
    float o0 = bout[0], o1 = bout[1], o2 = bout[2];
#pragma unroll
    for (int k = 0; k < 16; k++) {
        float v = h2[(size_t)n * 16 + k];
        o0 += v * Wout[k * 3 + 0];
        o1 += v * Wout[k * 3 + 1];
        o2 += v * Wout[k * 3 + 2];
    }
    out[n * 3 + 0] = o0;
    out[n * 3 + 1] = o1;
    out[n * 3 + 2] = o2;
}

extern "C" void kernel_launch(void* const* d_in, const int* in_sizes, int n_in,
                              void* d_out, int out_size, void* d_ws, size_t ws_size,
                              hipStream_t stream) {
    const float* x    = (const float*)d_in[0];
    const int* ei     = (const int*)d_in[1];   // [2,E]: row0=src, row1=dst
    const float* ew   = (const float*)d_in[2];
    const float* W1   = (const float*)d_in[3];
    const float* b1   = (const float*)d_in[4];
    const float* W2   = (const float*)d_in[5];
    const float* b2   = (const float*)d_in[6];
    const float* Wout = (const float*)d_in[7];
    const float* bout = (const float*)d_in[8];
    float* out = (float*)d_out;

    const int N = in_sizes[0] / 128;
    const int E = in_sizes[2];
    const int* src = ei;
    const int* dst = ei + E;
    const int B = (N + 255) >> 8;              // buckets of 256 nodes (391)

    // ws layout (4B words): recs[2E] | u1[32N] | h1[32N] | u2[16N] |
    //                       dinv[N] | blockHist[B*G] | bucketTotal[B] | bucketBase[B+1]
    // h2 aliases u1 (dead after agg<32>). recs at 0 -> 8B/128B alignment ok.
    float* ws = (float*)d_ws;
    uint2* recs = (uint2*)ws;
    float* u1   = ws + (size_t)2 * E;
    float* h1   = u1 + (size_t)32 * N;
    float* u2   = h1 + (size_t)32 * N;
    float* dinv = u2 + (size_t)16 * N;
    int* blockHist   = (int*)(dinv + N);
    int* bucketTotal = blockHist + (size_t)B * G;
    int* bucketBase  = bucketTotal + B;
    float* h2 = u1;

    hist_kernel<<<G, 256, 0, stream>>>(dst, blockHist, E, B);
    scan_cols_kernel<<<B, 256, 0, stream>>>(blockHist, bucketTotal);
    base_scan_kernel<<<1, 512, 0, stream>>>(bucketTotal, bucketBase, B, E);
    scatter_kernel<<<G, 256, 0, stream>>>(src, dst, ew, blockHist, bucketBase, recs, E, B);
    degdinv_kernel<<<B, 256, 0, stream>>>(bucketBase, recs, dinv, N);

    gemm1_kernel<<<(N + 7) / 8, 256, 0, stream>>>(x, W1, u1, N);
    agg_kernel<32><<<B, 256, 0, stream>>>(bucketBase, recs, u1, dinv, b1, h1, N);
    gemm2_kernel<<<(N + 15) / 16, 256, 0, stream>>>(h1, W2, u2, N);
    agg_kernel<16><<<B, 256, 0, stream>>>(bucketBase, recs, u2, dinv, b2, h2, N);
    final_kernel<<<(N + 255) / 256, 256, 0, stream>>>(h2, Wout, bout, out, N);
}

// Round 4
// 1252.063 us; speedup vs baseline: 1.0535x; 1.0535x over previous
//
#include <hip/hip_runtime.h>

// ---------------------------------------------------------------------------
// EnterpriseGNN: 3-layer GCN on MI355X.
//   h = relu( dinv[n] * ( sum_{e:dst=n} w_e * g[src_e]  +  g[n] ) + b )
//   g = dinv .* (x@W),  dinv = rsqrt(deg+1),  deg = sum_{e:dst=n} w_e.
//
// R1: per-(edge,feat) global atomics: 400 MB write-through, 332 us.
// R2: CSR-build random global atomics: hist alone 278 us (~23 G random
//     line-atomics/s is the wall).
// R3: bucket sort (256-node buckets) + LDS-tile agg: WRITE collapsed but
//     grid=391 WGs -> Occupancy 16%, serial gather chain, agg 700 us.
// R4: 64-node buckets (B=1563 WGs, ~6 blocks/CU, tile 8.4 KB) + dinv folded
//     into GEMM epilogue (g = dinv*u) so the edge loop is rec + one row
//     gather only. Zero random global atomics anywhere.
// ---------------------------------------------------------------------------

#define G 256            // producer blocks for hist/scatter
#define BSH 6            // log2(nodes per bucket)
#define BNODES 64
#define MAXB 1600        // >= ceil(100000/64)=1563

// --- bucket build ----------------------------------------------------------

__global__ __launch_bounds__(256) void hist_kernel(
    const int* __restrict__ dst, int* __restrict__ blockHist, int E, int B) {
    __shared__ int hist[MAXB];
    for (int i = threadIdx.x; i < B; i += 256) hist[i] = 0;
    __syncthreads();
    int per = (E + G - 1) / G;
    int e0 = blockIdx.x * per, e1 = min(e0 + per, E);
    for (int e = e0 + threadIdx.x; e < e1; e += 256)
        atomicAdd(&hist[((unsigned)dst[e]) >> BSH], 1);
    __syncthreads();
    for (int i = threadIdx.x; i < B; i += 256)
        blockHist[(size_t)i * G + blockIdx.x] = hist[i];
}

// exclusive scan over producers for one bucket; total -> bucketTotal[b]
__global__ __launch_bounds__(256) void scan_cols_kernel(
    int* __restrict__ blockHist, int* __restrict__ bucketTotal) {
    __shared__ int tmp[256];
    int b = blockIdx.x;
    int v = blockHist[(size_t)b * G + threadIdx.x];
    tmp[threadIdx.x] = v;
    __syncthreads();
    for (int off = 1; off < 256; off <<= 1) {
        int t = (threadIdx.x >= off) ? tmp[threadIdx.x - off] : 0;
        __syncthreads();
        tmp[threadIdx.x] += t;
        __syncthreads();
    }
    blockHist[(size_t)b * G + threadIdx.x] = tmp[threadIdx.x] - v;
    if (threadIdx.x == 255) bucketTotal[b] = tmp[255];
}

// exclusive scan of bucket totals (B <= 2048): 1024 threads, 2 per thread
__global__ __launch_bounds__(1024) void base_scan_kernel(
    const int* __restrict__ bucketTotal, int* __restrict__ bucketBase,
    int B, int E) {
    __shared__ int tmp[1024];
    int i0 = 2 * threadIdx.x, i1 = i0 + 1;
    int v0 = (i0 < B) ? bucketTotal[i0] : 0;
    int v1 = (i1 < B) ? bucketTotal[i1] : 0;
    tmp[threadIdx.x] = v0 + v1;
    __syncthreads();
    for (int off = 1; off < 1024; off <<= 1) {
        int t = (threadIdx.x >= off) ? tmp[threadIdx.x - off] : 0;
        __syncthreads();
        tmp[threadIdx.x] += t;
        __syncthreads();
    }
    int ex = tmp[threadIdx.x] - (v0 + v1);     // exclusive prefix of pair
    if (i0 < B) bucketBase[i0] = ex;
    if (i1 < B) bucketBase[i1] = ex + v0;
    if (threadIdx.x == 0) bucketBase[B] = E;
}

// rec.x = src | (dst & 63) << 20 ; rec.y = bits(w).
// Disjoint cursor ranges per (producer, bucket) -> LDS atomics only.
__global__ __launch_bounds__(256) void scatter_kernel(
    const int* __restrict__ src, const int* __restrict__ dst,
    const float* __restrict__ w, const int* __restrict__ blockHist,
    const int* __restrict__ bucketBase, uint2* __restrict__ recs,
    int E, int B) {
    __shared__ int cursor[MAXB];
    for (int i = threadIdx.x; i < B; i += 256)
        cursor[i] = bucketBase[i] + blockHist[(size_t)i * G + blockIdx.x];
    __syncthreads();
    int per = (E + G - 1) / G;
    int e0 = blockIdx.x * per, e1 = min(e0 + per, E);
    for (int e = e0 + threadIdx.x; e < e1; e += 256) {
        int d = dst[e];
        int b = ((unsigned)d) >> BSH;
        int pos = atomicAdd(&cursor[b], 1);     // LDS atomic
        recs[pos] = make_uint2((unsigned)src[e] |
                               ((unsigned)(d & (BNODES - 1)) << 20),
                               __float_as_uint(w[e]));
    }
}

// deg per bucket from records -> dinv = rsqrt(deg+1)
__global__ __launch_bounds__(256) void degdinv_kernel(
    const int* __restrict__ bucketBase, const uint2* __restrict__ recs,
    float* __restrict__ dinv, int N) {
    __shared__ float deg[BNODES];
    if (threadIdx.x < BNODES) deg[threadIdx.x] = 0.f;
    __syncthreads();
    int b = blockIdx.x;
    int r0 = bucketBase[b], r1 = bucketBase[b + 1];
    for (int i = r0 + threadIdx.x; i < r1; i += 256) {
        uint2 rec = recs[i];
        atomicAdd(&deg[rec.x >> 20], __uint_as_float(rec.y));
    }
    __syncthreads();
    if (threadIdx.x < BNODES) {
        int n = b * BNODES + threadIdx.x;
        if (n < N) dinv[n] = rsqrtf(deg[threadIdx.x] + 1.f);
    }
}

// --- dense layers ----------------------------------------------------------

// g1 = dinv .* (x @ W1)   (128 -> 32)
__global__ __launch_bounds__(256) void gemm1_kernel(
    const float* __restrict__ x, const float* __restrict__ W1,
    const float* __restrict__ dinv, float* __restrict__ g1, int N) {
    __shared__ float sW[128 * 32];   // 16 KB
    __shared__ float sx[8][128];     // 4 KB
    for (int i = threadIdx.x; i < 128 * 32; i += 256) sW[i] = W1[i];
    int node0 = blockIdx.x * 8;
    for (int i = threadIdx.x; i < 8 * 128; i += 256) {
        int r = i >> 7, c = i & 127;
        int n = node0 + r;
        sx[r][c] = (n < N) ? x[(size_t)n * 128 + c] : 0.f;
    }
    __syncthreads();
    int local = threadIdx.x >> 5;
    int j = threadIdx.x & 31;
    int n = node0 + local;
    if (n < N) {
        float acc = 0.f;
#pragma unroll 16
        for (int k = 0; k < 128; k++) acc += sx[local][k] * sW[k * 32 + j];
        g1[(size_t)n * 32 + j] = acc * dinv[n];
    }
}

// g2 = dinv .* (h1 @ W2)   (32 -> 16)
__global__ __launch_bounds__(256) void gemm2_kernel(
    const float* __restrict__ h1, const float* __restrict__ W2,
    const float* __restrict__ dinv, float* __restrict__ g2, int N) {
    __shared__ float sW[32 * 16];
    __shared__ float sin_[16][32];
    for (int i = threadIdx.x; i < 32 * 16; i += 256) sW[i] = W2[i];
    int node0 = blockIdx.x * 16;
    for (int i = threadIdx.x; i < 16 * 32; i += 256) {
        int r = i >> 5, c = i & 31;
        int n = node0 + r;
        sin_[r][c] = (n < N) ? h1[(size_t)n * 32 + c] : 0.f;
    }
    __syncthreads();
    int local = threadIdx.x >> 4;
    int j = threadIdx.x & 15;
    int n = node0 + local;
    if (n < N) {
        float acc = 0.f;
#pragma unroll
        for (int k = 0; k < 32; k++) acc += sin_[local][k] * sW[k * 16 + j];
        g2[(size_t)n * 16 + j] = acc * dinv[n];
    }
}

// one WG per 64-node bucket: LDS tile agg + fused self-loop/dinv/bias/relu
template <int F>
__global__ __launch_bounds__(256) void agg_kernel(
    const int* __restrict__ bucketBase, const uint2* __restrict__ recs,
    const float* __restrict__ g, const float* __restrict__ dinv,
    const float* __restrict__ bias, float* __restrict__ h, int N) {
    const int FS = F + 1;                       // bank-conflict pad
    __shared__ float tile[BNODES * FS];
    for (int i = threadIdx.x; i < BNODES * FS; i += 256) tile[i] = 0.f;
    __syncthreads();
    int b = blockIdx.x;
    int r0 = bucketBase[b], r1 = bucketBase[b + 1];
    const int EPB = 256 / F;                    // edges in flight / iteration
    int f = threadIdx.x & (F - 1);
    for (int i = r0 + (threadIdx.x / F); i < r1; i += EPB) {
        uint2 rec = recs[i];
        unsigned s  = rec.x & 0xFFFFFu;         // src (N < 2^20)
        unsigned dl = rec.x >> 20;              // dst & 63
        atomicAdd(&tile[dl * FS + f],
                  __uint_as_float(rec.y) * g[(size_t)s * F + f]);
    }
    __syncthreads();
    int node0 = b * BNODES;
    for (int k = threadIdx.x; k < BNODES * F; k += 256) {
        int loc = k / F, ff = k & (F - 1);
        int n = node0 + loc;
        if (n < N) {
            float di = dinv[n];
            float v = di * (tile[loc * FS + ff] + g[(size_t)n * F + ff]) + bias[ff];
            h[(size_t)n * F + ff] = fmaxf(v, 0.f);
        }
    }
}

// out = h2 @ Wout + bout   (16 -> 3)
__global__ __launch_bounds__(256) void final_kernel(
    const float* __restrict__ h2, const float* __restrict__ Wout,
    const float* __restrict__ bout, float* __restrict__ out, int N) {
    int n = blockIdx.x * blockDim.x + threadIdx.x;
    if (n >= N) return;
    float o0 = bout[0], o1 = bout[1], o2 = bout[2];
#pragma unroll
    for (int k = 0; k < 16; k++) {
        float v = h2[(size_t)n * 16 + k];
        o0 += v * Wout[k * 3 + 0];
        o1 += v * Wout[k * 3 + 1];
        o2 += v * Wout[k * 3 + 2];
    }
    out[n * 3 + 0] = o0;
    out[n * 3 + 1] = o1;
    out[n * 3 + 2] = o2;
}

extern "C" void kernel_launch(void* const* d_in, const int* in_sizes, int n_in,
                              void* d_out, int out_size, void* d_ws, size_t ws_size,
                              hipStream_t stream) {
    const float* x    = (const float*)d_in[0];
    const int* ei     = (const int*)d_in[1];   // [2,E]: row0=src, row1=dst
    const float* ew   = (const float*)d_in[2];
    const float* W1   = (const float*)d_in[3];
    const float* b1   = (const float*)d_in[4];
    const float* W2   = (const float*)d_in[5];
    const float* b2   = (const float*)d_in[6];
    const float* Wout = (const float*)d_in[7];
    const float* bout = (const float*)d_in[8];
    float* out = (float*)d_out;

    const int N = in_sizes[0] / 128;
    const int E = in_sizes[2];
    const int* src = ei;
    const int* dst = ei + E;
    const int B = (N + BNODES - 1) >> BSH;      // 1563 for N=100K

    // ws (4B words): recs[2E] | g1[32N] | h1[32N] | g2[16N] | dinv[N] |
    //                blockHist[B*G] | bucketTotal[B] | bucketBase[B+1]
    // h2 aliases g1 (dead after agg<32>).
    float* ws = (float*)d_ws;
    uint2* recs = (uint2*)ws;
    float* g1   = ws + (size_t)2 * E;
    float* h1   = g1 + (size_t)32 * N;
    float* g2   = h1 + (size_t)32 * N;
    float* dinv = g2 + (size_t)16 * N;
    int* blockHist   = (int*)(dinv + N);
    int* bucketTotal = blockHist + (size_t)B * G;
    int* bucketBase  = bucketTotal + B;
    float* h2 = g1;

    hist_kernel<<<G, 256, 0, stream>>>(dst, blockHist, E, B);
    scan_cols_kernel<<<B, 256, 0, stream>>>(blockHist, bucketTotal);
    base_scan_kernel<<<1, 1024, 0, stream>>>(bucketTotal, bucketBase, B, E);
    scatter_kernel<<<G, 256, 0, stream>>>(src, dst, ew, blockHist, bucketBase, recs, E, B);
    degdinv_kernel<<<B, 256, 0, stream>>>(bucketBase, recs, dinv, N);

    gemm1_kernel<<<(N + 7) / 8, 256, 0, stream>>>(x, W1, dinv, g1, N);
    agg_kernel<32><<<B, 256, 0, stream>>>(bucketBase, recs, g1, dinv, b1, h1, N);
    gemm2_kernel<<<(N + 15) / 16, 256, 0, stream>>>(h1, W2, dinv, g2, N);
    agg_kernel<16><<<B, 256, 0, stream>>>(bucketBase, recs, g2, dinv, b2, h2, N);
    final_kernel<<<(N + 255) / 256, 256, 0, stream>>>(h2, Wout, bout, out, N);
}

// Round 5
// 1120.599 us; speedup vs baseline: 1.1771x; 1.1173x over previous
//
#include <hip/hip_runtime.h>

// ---------------------------------------------------------------------------
// EnterpriseGNN: 3-layer GCN on MI355X.
//   h = relu( dinv[n] * ( sum_{e:dst=n} w_e * g[src_e]  +  g[n] ) + b )
//   g = dinv .* (x@W),  dinv = rsqrt(deg+1),  deg = sum_{e:dst=n} w_e.
//
// R1: per-(edge,feat) global atomics: 400 MB write-through, 332 us.
// R2: CSR-build random global atomics: ~23 G random line-atomics/s wall.
// R3: 256-node-bucket sort + LDS-tile agg: occupancy 16%, agg 700 us.
// R4: 64-node buckets: occupancy 40% but agg still 639 us — dependent-gather
//     latency chain, only 8 edges in flight per block (scalar loads).
// R5: MLP + fusion. float4 gathers with F/4 lanes/edge (32 edges in flight),
//     2x unroll (64 in flight), 32-node buckets (B=3125, ~8 blocks/CU).
//     gemm2 fused into agg1 epilogue (h1 stays in LDS), final matmul fused
//     into agg2 epilogue (h2 stays in LDS). Zero random global atomics.
// ---------------------------------------------------------------------------

#define G 256            // producer blocks for hist/scatter
#define BSH 5            // log2(nodes per bucket)
#define BNODES 32
#define MAXB 3200        // >= ceil(100000/32)=3125

// --- bucket build ----------------------------------------------------------

__global__ __launch_bounds__(256) void hist_kernel(
    const int* __restrict__ dst, int* __restrict__ blockHist, int E, int B) {
    __shared__ int hist[MAXB];
    for (int i = threadIdx.x; i < B; i += 256) hist[i] = 0;
    __syncthreads();
    int per = (E + G - 1) / G;
    int e0 = blockIdx.x * per, e1 = min(e0 + per, E);
    for (int e = e0 + threadIdx.x; e < e1; e += 256)
        atomicAdd(&hist[((unsigned)dst[e]) >> BSH], 1);
    __syncthreads();
    for (int i = threadIdx.x; i < B; i += 256)
        blockHist[(size_t)i * G + blockIdx.x] = hist[i];
}

// exclusive scan over producers for one bucket; total -> bucketTotal[b]
__global__ __launch_bounds__(256) void scan_cols_kernel(
    int* __restrict__ blockHist, int* __restrict__ bucketTotal) {
    __shared__ int tmp[256];
    int b = blockIdx.x;
    int v = blockHist[(size_t)b * G + threadIdx.x];
    tmp[threadIdx.x] = v;
    __syncthreads();
    for (int off = 1; off < 256; off <<= 1) {
        int t = (threadIdx.x >= off) ? tmp[threadIdx.x - off] : 0;
        __syncthreads();
        tmp[threadIdx.x] += t;
        __syncthreads();
    }
    blockHist[(size_t)b * G + threadIdx.x] = tmp[threadIdx.x] - v;
    if (threadIdx.x == 255) bucketTotal[b] = tmp[255];
}

// exclusive scan of bucket totals (B <= 4096): 1024 threads, 4 per thread
__global__ __launch_bounds__(1024) void base_scan_kernel(
    const int* __restrict__ bucketTotal, int* __restrict__ bucketBase,
    int B, int E) {
    __shared__ int tmp[1024];
    int v[4], s = 0;
#pragma unroll
    for (int k = 0; k < 4; k++) {
        int i = 4 * threadIdx.x + k;
        v[k] = (i < B) ? bucketTotal[i] : 0;
        s += v[k];
    }
    tmp[threadIdx.x] = s;
    __syncthreads();
    for (int off = 1; off < 1024; off <<= 1) {
        int t = (threadIdx.x >= off) ? tmp[threadIdx.x - off] : 0;
        __syncthreads();
        tmp[threadIdx.x] += t;
        __syncthreads();
    }
    int ex = tmp[threadIdx.x] - s;
#pragma unroll
    for (int k = 0; k < 4; k++) {
        int i = 4 * threadIdx.x + k;
        if (i < B) bucketBase[i] = ex;
        ex += v[k];
    }
    if (threadIdx.x == 0) bucketBase[B] = E;
}

// rec.x = src | (dst & 31) << 20 ; rec.y = bits(w).
// Disjoint cursor ranges per (producer, bucket) -> LDS atomics only.
__global__ __launch_bounds__(256) void scatter_kernel(
    const int* __restrict__ src, const int* __restrict__ dst,
    const float* __restrict__ w, const int* __restrict__ blockHist,
    const int* __restrict__ bucketBase, uint2* __restrict__ recs,
    int E, int B) {
    __shared__ int cursor[MAXB];
    for (int i = threadIdx.x; i < B; i += 256)
        cursor[i] = bucketBase[i] + blockHist[(size_t)i * G + blockIdx.x];
    __syncthreads();
    int per = (E + G - 1) / G;
    int e0 = blockIdx.x * per, e1 = min(e0 + per, E);
    for (int e = e0 + threadIdx.x; e < e1; e += 256) {
        int d = dst[e];
        int b = ((unsigned)d) >> BSH;
        int pos = atomicAdd(&cursor[b], 1);     // LDS atomic
        recs[pos] = make_uint2((unsigned)src[e] |
                               ((unsigned)(d & (BNODES - 1)) << 20),
                               __float_as_uint(w[e]));
    }
}

// deg per bucket from records -> dinv = rsqrt(deg+1)
__global__ __launch_bounds__(256) void degdinv_kernel(
    const int* __restrict__ bucketBase, const uint2* __restrict__ recs,
    float* __restrict__ dinv, int N) {
    __shared__ float deg[BNODES];
    if (threadIdx.x < BNODES) deg[threadIdx.x] = 0.f;
    __syncthreads();
    int b = blockIdx.x;
    int r0 = bucketBase[b], r1 = bucketBase[b + 1];
    for (int i = r0 + threadIdx.x; i < r1; i += 256) {
        uint2 rec = recs[i];
        atomicAdd(&deg[rec.x >> 20], __uint_as_float(rec.y));
    }
    __syncthreads();
    if (threadIdx.x < BNODES) {
        int n = b * BNODES + threadIdx.x;
        if (n < N) dinv[n] = rsqrtf(deg[threadIdx.x] + 1.f);
    }
}

// --- g1 = dinv .* (x @ W1)   (128 -> 32) -----------------------------------

__global__ __launch_bounds__(256) void gemm1_kernel(
    const float* __restrict__ x, const float* __restrict__ W1,
    const float* __restrict__ dinv, float* __restrict__ g1, int N) {
    __shared__ float sW[128 * 32];   // 16 KB
    __shared__ float sx[8][128];     // 4 KB
    for (int i = threadIdx.x; i < 128 * 32; i += 256) sW[i] = W1[i];
    int node0 = blockIdx.x * 8;
    for (int i = threadIdx.x; i < 8 * 128; i += 256) {
        int r = i >> 7, c = i & 127;
        int n = node0 + r;
        sx[r][c] = (n < N) ? x[(size_t)n * 128 + c] : 0.f;
    }
    __syncthreads();
    int local = threadIdx.x >> 5;
    int j = threadIdx.x & 31;
    int n = node0 + local;
    if (n < N) {
        float acc = 0.f;
#pragma unroll 16
        for (int k = 0; k < 128; k++) acc += sx[local][k] * sW[k * 32 + j];
        g1[(size_t)n * 32 + j] = acc * dinv[n];
    }
}

// --- agg1: edges over g1 -> h1 (LDS) -> g2 = dinv.*(h1@W2) -----------------
// F=32: 8 lanes/edge (float4), 32 edges in flight, 2x unroll.

__global__ __launch_bounds__(256) void agg1_kernel(
    const int* __restrict__ bucketBase, const uint2* __restrict__ recs,
    const float* __restrict__ g1, const float* __restrict__ dinv,
    const float* __restrict__ b1, const float* __restrict__ W2,
    float* __restrict__ g2, int N) {
    const int FS = 33;
    __shared__ float tile[BNODES * FS];          // 4.2 KB
    __shared__ float sW2[32 * 16];               // 2 KB
    for (int i = threadIdx.x; i < BNODES * FS; i += 256) tile[i] = 0.f;
    for (int i = threadIdx.x; i < 32 * 16; i += 256) sW2[i] = W2[i];
    __syncthreads();

    int b = blockIdx.x;
    int r0 = bucketBase[b], r1 = bucketBase[b + 1];
    const float4* g4 = (const float4*)g1;
    int eg = threadIdx.x >> 3;                   // edge slot 0..31
    int l  = threadIdx.x & 7;                    // float4 lane within row

    for (int i = r0 + eg; i < r1; i += 64) {
        int j = i + 32;
        uint2 ra = recs[i];
        unsigned sa = ra.x & 0xFFFFFu, da = ra.x >> 20;
        float wa = __uint_as_float(ra.y);
        float4 va = g4[(size_t)sa * 8 + l];
        bool vb = (j < r1);
        unsigned sb = 0, db = 0; float wb = 0.f; float4 vbv;
        uint2 rb;
        if (vb) {
            rb = recs[j];
            sb = rb.x & 0xFFFFFu; db = rb.x >> 20;
            wb = __uint_as_float(rb.y);
            vbv = g4[(size_t)sb * 8 + l];
        }
        int ba = da * FS + 4 * l;
        atomicAdd(&tile[ba + 0], wa * va.x);
        atomicAdd(&tile[ba + 1], wa * va.y);
        atomicAdd(&tile[ba + 2], wa * va.z);
        atomicAdd(&tile[ba + 3], wa * va.w);
        if (vb) {
            int bb = db * FS + 4 * l;
            atomicAdd(&tile[bb + 0], wb * vbv.x);
            atomicAdd(&tile[bb + 1], wb * vbv.y);
            atomicAdd(&tile[bb + 2], wb * vbv.z);
            atomicAdd(&tile[bb + 3], wb * vbv.w);
        }
    }
    __syncthreads();

    // h1 = relu(dinv*(tile + g1_self) + b1), back into tile (in-place per
    // thread: each thread reads/writes only its own 4 slots).
    int loc = threadIdx.x >> 3;                  // node 0..31
    int n = b * BNODES + loc;
    int t0 = loc * FS + 4 * l;
    float4 hv = make_float4(0.f, 0.f, 0.f, 0.f);
    if (n < N) {
        float di = dinv[n];
        float4 gv = g4[(size_t)n * 8 + l];
        float4 b4 = ((const float4*)b1)[l];
        hv.x = fmaxf(di * (tile[t0 + 0] + gv.x) + b4.x, 0.f);
        hv.y = fmaxf(di * (tile[t0 + 1] + gv.y) + b4.y, 0.f);
        hv.z = fmaxf(di * (tile[t0 + 2] + gv.z) + b4.z, 0.f);
        hv.w = fmaxf(di * (tile[t0 + 3] + gv.w) + b4.w, 0.f);
    }
    tile[t0 + 0] = hv.x; tile[t0 + 1] = hv.y;
    tile[t0 + 2] = hv.z; tile[t0 + 3] = hv.w;
    __syncthreads();

    // g2[n][j] = dinv[n] * sum_k h1[n][k] * W2[k][j]   (512 outputs, 2/thread)
    for (int o = threadIdx.x; o < BNODES * 16; o += 256) {
        int lc = o >> 4, jj = o & 15;
        int nn = b * BNODES + lc;
        if (nn < N) {
            float acc = 0.f;
#pragma unroll
            for (int k = 0; k < 32; k++) acc += tile[lc * FS + k] * sW2[k * 16 + jj];
            g2[(size_t)nn * 16 + jj] = acc * dinv[nn];
        }
    }
}

// --- agg2: edges over g2 -> h2 (LDS) -> out = h2@Wout + bout ---------------
// F=16: 4 lanes/edge (float4), 64 edges in flight, 2x unroll.

__global__ __launch_bounds__(256) void agg2_kernel(
    const int* __restrict__ bucketBase, const uint2* __restrict__ recs,
    const float* __restrict__ g2, const float* __restrict__ dinv,
    const float* __restrict__ b2, const float* __restrict__ Wout,
    const float* __restrict__ bout, float* __restrict__ out, int N) {
    const int FS = 17;
    __shared__ float tile[BNODES * FS];          // 2.2 KB
    __shared__ float sWo[48];
    __shared__ float sbo[3];
    for (int i = threadIdx.x; i < BNODES * FS; i += 256) tile[i] = 0.f;
    if (threadIdx.x < 48) sWo[threadIdx.x] = Wout[threadIdx.x];
    if (threadIdx.x < 3) sbo[threadIdx.x] = bout[threadIdx.x];
    __syncthreads();

    int b = blockIdx.x;
    int r0 = bucketBase[b], r1 = bucketBase[b + 1];
    const float4* g4 = (const float4*)g2;
    int eg = threadIdx.x >> 2;                   // edge slot 0..63
    int l  = threadIdx.x & 3;

    for (int i = r0 + eg; i < r1; i += 128) {
        int j = i + 64;
        uint2 ra = recs[i];
        unsigned sa = ra.x & 0xFFFFFu, da = ra.x >> 20;
        float wa = __uint_as_float(ra.y);
        float4 va = g4[(size_t)sa * 4 + l];
        bool vb = (j < r1);
        unsigned sb = 0, db = 0; float wb = 0.f; float4 vbv;
        uint2 rb;
        if (vb) {
            rb = recs[j];
            sb = rb.x & 0xFFFFFu; db = rb.x >> 20;
            wb = __uint_as_float(rb.y);
            vbv = g4[(size_t)sb * 4 + l];
        }
        int ba = da * FS + 4 * l;
        atomicAdd(&tile[ba + 0], wa * va.x);
        atomicAdd(&tile[ba + 1], wa * va.y);
        atomicAdd(&tile[ba + 2], wa * va.z);
        atomicAdd(&tile[ba + 3], wa * va.w);
        if (vb) {
            int bb = db * FS + 4 * l;
            atomicAdd(&tile[bb + 0], wb * vbv.x);
            atomicAdd(&tile[bb + 1], wb * vbv.y);
            atomicAdd(&tile[bb + 2], wb * vbv.z);
            atomicAdd(&tile[bb + 3], wb * vbv.w);
        }
    }
    __syncthreads();

    // h2 = relu(dinv*(tile + g2_self) + b2), back into tile (128 threads)
    if (threadIdx.x < 128) {
        int loc = threadIdx.x >> 2;
        int ll = threadIdx.x & 3;
        int n = b * BNODES + loc;
        int t0 = loc * FS + 4 * ll;
        float4 hv = make_float4(0.f, 0.f, 0.f, 0.f);
        if (n < N) {
            float di = dinv[n];
            float4 gv = g4[(size_t)n * 4 + ll];
            float4 b4 = ((const float4*)b2)[ll];
            hv.x = fmaxf(di * (tile[t0 + 0] + gv.x) + b4.x, 0.f);
            hv.y = fmaxf(di * (tile[t0 + 1] + gv.y) + b4.y, 0.f);
            hv.z = fmaxf(di * (tile[t0 + 2] + gv.z) + b4.z, 0.f);
            hv.w = fmaxf(di * (tile[t0 + 3] + gv.w) + b4.w, 0.f);
        }
        tile[t0 + 0] = hv.x; tile[t0 + 1] = hv.y;
        tile[t0 + 2] = hv.z; tile[t0 + 3] = hv.w;
    }
    __syncthreads();

    // out[n][c] = h2[n] . Wout[:,c] + bout[c]   (96 threads)
    if (threadIdx.x < 96) {
        int loc = threadIdx.x / 3;
        int c = threadIdx.x - 3 * loc;
        int n = b * BNODES + loc;
        if (n < N) {
            float acc = sbo[c];
#pragma unroll
            for (int k = 0; k < 16; k++) acc += tile[loc * FS + k] * sWo[k * 3 + c];
            out[(size_t)n * 3 + c] = acc;
        }
    }
}

extern "C" void kernel_launch(void* const* d_in, const int* in_sizes, int n_in,
                              void* d_out, int out_size, void* d_ws, size_t ws_size,
                              hipStream_t stream) {
    const float* x    = (const float*)d_in[0];
    const int* ei     = (const int*)d_in[1];   // [2,E]: row0=src, row1=dst
    const float* ew   = (const float*)d_in[2];
    const float* W1   = (const float*)d_in[3];
    const float* b1   = (const float*)d_in[4];
    const float* W2   = (const float*)d_in[5];
    const float* b2   = (const float*)d_in[6];
    const float* Wout = (const float*)d_in[7];
    const float* bout = (const float*)d_in[8];
    float* out = (float*)d_out;

    const int N = in_sizes[0] / 128;
    const int E = in_sizes[2];
    const int* src = ei;
    const int* dst = ei + E;
    const int B = (N + BNODES - 1) >> BSH;      // 3125 for N=100K

    // ws (4B words): recs[2E] | g1[32N] | g2[16N] | dinv[N] |
    //                blockHist[B*G] | bucketTotal[B] | bucketBase[B+1]
    float* ws = (float*)d_ws;
    uint2* recs = (uint2*)ws;
    float* g1   = ws + (size_t)2 * E;
    float* g2   = g1 + (size_t)32 * N;
    float* dinv = g2 + (size_t)16 * N;
    int* blockHist   = (int*)(dinv + N);
    int* bucketTotal = blockHist + (size_t)B * G;
    int* bucketBase  = bucketTotal + B;

    hist_kernel<<<G, 256, 0, stream>>>(dst, blockHist, E, B);
    scan_cols_kernel<<<B, 256, 0, stream>>>(blockHist, bucketTotal);
    base_scan_kernel<<<1, 1024, 0, stream>>>(bucketTotal, bucketBase, B, E);
    scatter_kernel<<<G, 256, 0, stream>>>(src, dst, ew, blockHist, bucketBase, recs, E, B);
    degdinv_kernel<<<B, 256, 0, stream>>>(bucketBase, recs, dinv, N);

    gemm1_kernel<<<(N + 7) / 8, 256, 0, stream>>>(x, W1, dinv, g1, N);
    agg1_kernel<<<B, 256, 0, stream>>>(bucketBase, recs, g1, dinv, b1, W2, g2, N);
    agg2_kernel<<<B, 256, 0, stream>>>(bucketBase, recs, g2, dinv, b2, Wout, bout, out, N);
}